// Round 7
// baseline (17924.872 us; speedup 1.0000x reference)
//
#include <hip/hip_runtime.h>
#include <hip/hip_fp16.h>

// ============================================================================
// ATTNAligner forward. R7: lstm_scan rewritten — weights pinned in PHYSICAL
// AGPRs via explicit v_accvgpr_write/read inline asm (R2-R6: allocator spilled
// or sank every virtual-register form; 4 failed rounds at VGPR_Count~128).
// Thread=cell mapping: half0 threads own rows {i,f} and cell state, half1 own
// {g,o}; gate exchange via 2KB LDS. kg0-8 LDS, kg9-24 AGPR, kg25-31 streamed.
// ============================================================================

typedef unsigned int u32;
typedef _Float16 h2_t __attribute__((ext_vector_type(2)));
typedef _Float16 f16x8 __attribute__((ext_vector_type(8)));
typedef float f32x4 __attribute__((ext_vector_type(4)));
union U32H2 { u32 u; h2_t h; };

#define T_LEN 1000
#define BATCH 16
#define SROWS (T_LEN * BATCH)

__device__ __forceinline__ float dot2f(u32 a, u32 b, float c) {
#if __has_builtin(__builtin_amdgcn_fdot2)
    U32H2 ua; ua.u = a; U32H2 ub; ub.u = b;
    return __builtin_amdgcn_fdot2(ua.h, ub.h, c, false);
#else
    U32H2 ua; ua.u = a; U32H2 ub; ub.u = b;
    return c + (float)ua.h.x * (float)ub.h.x + (float)ua.h.y * (float)ub.h.y;
#endif
}

__device__ __forceinline__ u32 pack2h(float a, float b) {
    h2_t p; p.x = (_Float16)a; p.y = (_Float16)b;
    U32H2 u; u.h = p; return u.u;
}

__device__ __forceinline__ float fsigm(float x) { return 1.0f / (1.0f + __expf(-x)); }
__device__ __forceinline__ float ftanh_(float x) {
    x = fminf(fmaxf(x, -15.0f), 15.0f);
    float e = __expf(-2.0f * x);
    return (1.0f - e) / (1.0f + e);
}

// ---------------------------------------------------------------------------
// Generic transpose: src[R][C] -> dst[C][R]  (fp32; ctc/mel head weights)
// ---------------------------------------------------------------------------
__global__ void transpose_kernel(const float* __restrict__ src, float* __restrict__ dst,
                                 int R, int C) {
    int total = R * C;
    for (int i = blockIdx.x * blockDim.x + threadIdx.x; i < total; i += gridDim.x * blockDim.x) {
        int r = i / C, c = i - r * C;
        dst[(size_t)c * R + r] = src[i];
    }
}

// ---------------------------------------------------------------------------
// Pack recurrent weights Whh [layers][2][1024][256] f32
//   -> wp [l][d][kg 32][row 1024][q 4] u32 = half2(W[row][8kg+2q], W[row][8kg+2q+1])
// ---------------------------------------------------------------------------
__global__ void prep_whh_kernel(const float* __restrict__ whh, u32* __restrict__ wp, int total) {
    for (int idx = blockIdx.x * blockDim.x + threadIdx.x; idx < total; idx += gridDim.x * blockDim.x) {
        int q = idx & 3;
        int j = (idx >> 2) & 1023;
        int g = (idx >> 12) & 31;
        int d = (idx >> 17) & 1;
        int l = idx >> 18;
        int k = g * 8 + q * 2;
        const float* s = whh + ((size_t)(l * 2 + d) * 1024 + j) * 256 + k;
        wp[idx] = pack2h(s[0], s[1]);
    }
}

// ---------------------------------------------------------------------------
// Pack a weight matrix into MFMA-16x16x32 B-fragment order (fp16).
// ---------------------------------------------------------------------------
__global__ void pack_b_kernel(const float* __restrict__ src, _Float16* __restrict__ dst,
                              int N, int K, int sn, int sk, int off) {
    int total = N * K;
    int kst = K >> 5;
    for (int idx = blockIdx.x * blockDim.x + threadIdx.x; idx < total; idx += gridDim.x * blockDim.x) {
        int i = idx & 7;
        int lane = (idx >> 3) & 63;
        int rest = idx >> 9;
        int ks = rest % kst;
        int nt = rest / kst;
        int n = nt * 16 + (lane & 15);
        int k = ks * 32 + (lane >> 4) * 8 + i;
        dst[idx] = (_Float16)src[(size_t)n * sn + (size_t)k * sk + off];
    }
}

// ---------------------------------------------------------------------------
// Conv1: mels [B][80][T] (normalized inline) -> y1 [B][512][T] fp32, K=5 + BN
// ---------------------------------------------------------------------------
__global__ __launch_bounds__(256) void conv1_kernel(
    const float* __restrict__ mels, const float* __restrict__ w,
    const float* __restrict__ cbias, const float* __restrict__ bg,
    const float* __restrict__ bb, const float* __restrict__ bm,
    const float* __restrict__ bv, float* __restrict__ y1)
{
    __shared__ float xin[80 * 72];
    int t0 = blockIdx.x * 64;
    int b = blockIdx.y;
    int tid = threadIdx.x;
    for (int idx = tid; idx < 80 * 68; idx += 256) {
        int m = idx / 68, i = idx - m * 68;
        int t = t0 - 4 + i;
        float v = 0.0f;
        if (t >= 0 && t < T_LEN) v = mels[(size_t)(b * 80 + m) * T_LEN + t] * (1.0f / 6.0f) + 1.0f;
        xin[m * 72 + i] = v;
    }
    __syncthreads();
    int tg = tid & 15, cl = tid >> 4;
    for (int pass = 0; pass < 32; ++pass) {
        int c = pass * 16 + cl;
        const float* wc = w + (size_t)c * 400;
        float a0 = 0, a1 = 0, a2 = 0, a3 = 0;
        for (int m = 0; m < 80; ++m) {
            float4 xa = *(const float4*)&xin[m * 72 + tg * 4];
            float4 xb = *(const float4*)&xin[m * 72 + tg * 4 + 4];
            float w0 = wc[m * 5 + 0], w1 = wc[m * 5 + 1], w2 = wc[m * 5 + 2];
            float w3 = wc[m * 5 + 3], w4 = wc[m * 5 + 4];
            a0 += w0 * xa.x + w1 * xa.y + w2 * xa.z + w3 * xa.w + w4 * xb.x;
            a1 += w0 * xa.y + w1 * xa.z + w2 * xa.w + w3 * xb.x + w4 * xb.y;
            a2 += w0 * xa.z + w1 * xa.w + w2 * xb.x + w3 * xb.y + w4 * xb.z;
            a3 += w0 * xa.w + w1 * xb.x + w2 * xb.y + w3 * xb.z + w4 * xb.w;
        }
        float scale = bg[c] * rsqrtf(bv[c] + 1e-5f);
        float shift = (cbias[c] - bm[c]) * scale + bb[c];
        int tb = t0 + tg * 4;
        float* yp = y1 + (size_t)(b * 512 + c) * T_LEN + tb;
        if (tb + 0 < T_LEN) yp[0] = a0 * scale + shift;
        if (tb + 1 < T_LEN) yp[1] = a1 * scale + shift;
        if (tb + 2 < T_LEN) yp[2] = a2 * scale + shift;
        if (tb + 3 < T_LEN) yp[3] = a3 * scale + shift;
    }
}

// ---------------------------------------------------------------------------
// Relayout conv1 output: y1 [B][512][T] fp32 -> f0 [(t*16+b)][512] fp16
// ---------------------------------------------------------------------------
__global__ __launch_bounds__(256) void relayout_kernel(
    const float* __restrict__ y1, _Float16* __restrict__ dst)
{
    __shared__ float tile[64][65];
    int t0 = blockIdx.x * 64;
    int c0 = blockIdx.y * 64;
    int b = blockIdx.z;
    int tid = threadIdx.x;
#pragma unroll
    for (int q = 0; q < 16; ++q) {
        int lin = tid + q * 256;
        int cl = lin >> 6, tl = lin & 63;
        int t = t0 + tl;
        tile[cl][tl] = (t < T_LEN) ? y1[(size_t)(b * 512 + c0 + cl) * T_LEN + t] : 0.0f;
    }
    __syncthreads();
#pragma unroll
    for (int q = 0; q < 16; ++q) {
        int lin = tid + q * 256;
        int rl = lin >> 6, cc = lin & 63;
        int t = t0 + rl;
        if (t < T_LEN)
            dst[(size_t)(t * BATCH + b) * 512 + c0 + cc] = (_Float16)tile[cc][rl];
    }
}

// ---------------------------------------------------------------------------
// MFMA fp16 GEMM (unchanged from R6).
// ---------------------------------------------------------------------------
template<int MODE>
__global__ __launch_bounds__(512, 2) void gemm_mfma(
    const _Float16* __restrict__ A, const _Float16* __restrict__ A2, int K1,
    const uint4* __restrict__ Bp, const float* __restrict__ bias,
    float* __restrict__ C32, _Float16* __restrict__ C16,
    const float* __restrict__ cvb, const float* __restrict__ bg,
    const float* __restrict__ bb, const float* __restrict__ bm,
    const float* __restrict__ bv, int N, int K)
{
    __shared__ _Float16 At[128 * 40];
    const int m0 = blockIdx.x * 128, n0 = blockIdx.y * 128;
    const int tid = threadIdx.x, lane = tid & 63, w = tid >> 6;
    const int wm = w >> 2, wn = w & 3;
    const int srow = tid >> 2, sseg = tid & 3;
    const int ksteps = K >> 5;
    f32x4 acc[4][2];
#pragma unroll
    for (int i = 0; i < 4; ++i) { acc[i][0] = (f32x4)0.0f; acc[i][1] = (f32x4)0.0f; }

    for (int ks = 0; ks < ksteps; ++ks) {
        int k0 = ks << 5;
        uint4 av;
        if (MODE == 1) {
            int kph = k0 >> 9, kk = k0 & 511;
            int rsrc = m0 + srow + (kph - 4) * 16;
            if (rsrc >= 0) av = *(const uint4*)(A + (size_t)rsrc * 512 + kk + sseg * 8);
            else { av.x = av.y = av.z = av.w = 0u; }
        } else {
            int col = k0 + sseg * 8;
            const _Float16* src = (col < K1) ? (A + (size_t)(m0 + srow) * K1 + col)
                                             : (A2 + (size_t)(m0 + srow) * (K - K1) + (col - K1));
            av = *(const uint4*)src;
        }
        __syncthreads();
        *(uint4*)&At[srow * 40 + sseg * 8] = av;
        __syncthreads();

        f16x8 bf[2];
#pragma unroll
        for (int ct = 0; ct < 2; ++ct) {
            int nt = (n0 >> 4) + wn * 2 + ct;
            int bblk = (MODE == 1) ? ((ks >> 4) * 512 + nt * 16 + (ks & 15))
                                   : (nt * ksteps + ks);
            uint4 braw = Bp[(size_t)bblk * 64 + lane];
            bf[ct] = *(f16x8*)&braw;
        }
#pragma unroll
        for (int rt = 0; rt < 4; ++rt) {
            f16x8 af = *(f16x8*)&At[(wm * 64 + rt * 16 + (lane & 15)) * 40 + (lane >> 4) * 8];
            acc[rt][0] = __builtin_amdgcn_mfma_f32_16x16x32_f16(af, bf[0], acc[rt][0], 0, 0, 0);
            acc[rt][1] = __builtin_amdgcn_mfma_f32_16x16x32_f16(af, bf[1], acc[rt][1], 0, 0, 0);
        }
    }

    const int r0 = m0 + wm * 64 + (lane >> 4) * 4;
    const int cb0 = n0 + wn * 32 + (lane & 15);
#pragma unroll
    for (int ct = 0; ct < 2; ++ct) {
        int col = cb0 + ct * 16;
        float badd = 0.0f, sc = 0.0f, sh = 0.0f;
        if (MODE == 0) { if (bias) badd = bias[col]; }
        else {
            sc = bg[col] * rsqrtf(bv[col] + 1e-5f);
            sh = (cvb[col] - bm[col]) * sc + bb[col];
        }
#pragma unroll
        for (int rt = 0; rt < 4; ++rt) {
#pragma unroll
            for (int rr = 0; rr < 4; ++rr) {
                int row = r0 + rt * 16 + rr;
                float v = acc[rt][ct][rr];
                if (MODE == 0) C32[(size_t)row * N + col] = v + badd;
                else           C16[(size_t)row * 512 + col] = (_Float16)(v * sc + sh);
            }
        }
    }
}

// ---------------------------------------------------------------------------
// LSTM scan (R7). One block per (batch, dir), 512 threads.
// half = tid>>8: half0 -> rows {j, 256+j} (i,f) + cell state; half1 -> {512+j,
// 768+j} (g,o). kg0-8 LDS (144KB), kg9-24 in AGPRs a0..a127, kg25-31 streamed.
// ---------------------------------------------------------------------------
#define SCAN_LDS (147456 + 512 + 2048)

#define ACLOBS \
  "a0","a1","a2","a3","a4","a5","a6","a7","a8","a9","a10","a11","a12","a13","a14","a15", \
  "a16","a17","a18","a19","a20","a21","a22","a23","a24","a25","a26","a27","a28","a29","a30","a31", \
  "a32","a33","a34","a35","a36","a37","a38","a39","a40","a41","a42","a43","a44","a45","a46","a47", \
  "a48","a49","a50","a51","a52","a53","a54","a55","a56","a57","a58","a59","a60","a61","a62","a63", \
  "a64","a65","a66","a67","a68","a69","a70","a71","a72","a73","a74","a75","a76","a77","a78","a79", \
  "a80","a81","a82","a83","a84","a85","a86","a87","a88","a89","a90","a91","a92","a93","a94","a95", \
  "a96","a97","a98","a99","a100","a101","a102","a103","a104","a105","a106","a107","a108","a109","a110","a111", \
  "a112","a113","a114","a115","a116","a117","a118","a119","a120","a121","a122","a123","a124","a125","a126","a127"

#define AST(i0,i1,i2,i3, V) \
    asm volatile("v_accvgpr_write_b32 a" #i0 ", %0\n\t" \
                 "v_accvgpr_write_b32 a" #i1 ", %1\n\t" \
                 "v_accvgpr_write_b32 a" #i2 ", %2\n\t" \
                 "v_accvgpr_write_b32 a" #i3 ", %3" \
                 :: "v"((V).x), "v"((V).y), "v"((V).z), "v"((V).w) : ACLOBS)

#define ARD(N, D) asm volatile("v_accvgpr_read_b32 %0, a" #N : "=v"(D))

#define STAGE2(kg, A0,A1,A2,A3, B0,B1,B2,B3) { \
    uint4 t0_ = wp[(kg) * 1024 + r0]; AST(A0,A1,A2,A3, t0_); \
    uint4 t1_ = wp[(kg) * 1024 + r1]; AST(B0,B1,B2,B3, t1_); }

#define AGRP(kg, A0,A1,A2,A3, B0,B1,B2,B3) { \
    uint4 hv = h4[kg]; \
    u32 ta0,ta1,ta2,ta3,tb0,tb1,tb2,tb3; \
    ARD(A0,ta0); ARD(A1,ta1); ARD(A2,ta2); ARD(A3,ta3); \
    ARD(B0,tb0); ARD(B1,tb1); ARD(B2,tb2); ARD(B3,tb3); \
    acc0 = dot2f(hv.x,ta0,acc0); acc0 = dot2f(hv.y,ta1,acc0); \
    acc0 = dot2f(hv.z,ta2,acc0); acc0 = dot2f(hv.w,ta3,acc0); \
    acc1 = dot2f(hv.x,tb0,acc1); acc1 = dot2f(hv.y,tb1,acc1); \
    acc1 = dot2f(hv.z,tb2,acc1); acc1 = dot2f(hv.w,tb3,acc1); }

#define SG7(M) M(25) M(26) M(27) M(28) M(29) M(30) M(31)

__global__ __launch_bounds__(512) __attribute__((amdgpu_waves_per_eu(2, 2)))
void lstm_scan(
    const float* __restrict__ pre, const uint4* __restrict__ WPl,
    float* __restrict__ out32, _Float16* __restrict__ out16)
{
    const int b = blockIdx.x >> 1;
    const int dir = blockIdx.x & 1;
    const int tid = threadIdx.x;
    const int half = tid >> 8;
    const int j = tid & 255;
    const int r0 = half * 512 + j;        // i-gate row (half0) / g-gate row (half1)
    const int r1 = half * 512 + 256 + j;  // f-gate row / o-gate row

    extern __shared__ char smem[];
    uint4* wl = (uint4*)smem;                     // [9][1024] uint4 weights
    uint4* h4 = (uint4*)(smem + 147456);          // [32] uint4 = 128 u32 packed h
    float* gx = (float*)(smem + 147456 + 512);    // [256][2] g/o preacts

    const uint4* wp = WPl + (size_t)dir * 32768;  // [32 kg][1024 row]

    for (int i = tid; i < 9216; i += 512) wl[i] = wp[i];

    // Stage kg 9..24 into physical AGPRs a0..a127 (8 per group: r0 q0-3, r1 q0-3)
    STAGE2(9,   0,1,2,3,     4,5,6,7)
    STAGE2(10,  8,9,10,11,   12,13,14,15)
    STAGE2(11,  16,17,18,19, 20,21,22,23)
    STAGE2(12,  24,25,26,27, 28,29,30,31)
    STAGE2(13,  32,33,34,35, 36,37,38,39)
    STAGE2(14,  40,41,42,43, 44,45,46,47)
    STAGE2(15,  48,49,50,51, 52,53,54,55)
    STAGE2(16,  56,57,58,59, 60,61,62,63)
    STAGE2(17,  64,65,66,67, 68,69,70,71)
    STAGE2(18,  72,73,74,75, 76,77,78,79)
    STAGE2(19,  80,81,82,83, 84,85,86,87)
    STAGE2(20,  88,89,90,91, 92,93,94,95)
    STAGE2(21,  96,97,98,99, 100,101,102,103)
    STAGE2(22,  104,105,106,107, 108,109,110,111)
    STAGE2(23,  112,113,114,115, 116,117,118,119)
    STAGE2(24,  120,121,122,123, 124,125,126,127)

    u32* h16 = (u32*)h4;
    if (tid < 128) h16[tid] = 0u;
    float c = 0.0f;
    __syncthreads();

    // software-pipelined pre-activation rows
    int tt0 = dir ? (T_LEN - 1) : 0;
    const float* pr0 = pre + (size_t)(tt0 * BATCH + b) * 2048 + (dir << 10);
    float p0 = pr0[r0], p1 = pr0[r1];

    for (int step = 0; step < T_LEN; ++step) {
        // keep compiler's AGPR-spiller out of a0..a127 inside the loop
        asm volatile("" ::: ACLOBS);
        int tt = dir ? (T_LEN - 1 - step) : step;
        float acc0 = p0, acc1 = p1;
        if (step + 1 < T_LEN) {
            int tn = dir ? (T_LEN - 2 - step) : (step + 1);
            const float* pn = pre + (size_t)(tn * BATCH + b) * 2048 + (dir << 10);
            p0 = pn[r0]; p1 = pn[r1];
        }
        // streamed kg 25..31: issue all loads early (consumed after AGPR dots)
#define DECLS(kg) uint4 sa##kg = wp[kg * 1024 + r0]; uint4 sb##kg = wp[kg * 1024 + r1];
        SG7(DECLS)
#undef DECLS
        // LDS groups 0..8
#pragma unroll
        for (int g = 0; g < 9; ++g) {
            uint4 hv = h4[g];
            uint4 w0 = wl[g * 1024 + r0];
            uint4 w1 = wl[g * 1024 + r1];
            acc0 = dot2f(hv.x, w0.x, acc0); acc0 = dot2f(hv.y, w0.y, acc0);
            acc0 = dot2f(hv.z, w0.z, acc0); acc0 = dot2f(hv.w, w0.w, acc0);
            acc1 = dot2f(hv.x, w1.x, acc1); acc1 = dot2f(hv.y, w1.y, acc1);
            acc1 = dot2f(hv.z, w1.z, acc1); acc1 = dot2f(hv.w, w1.w, acc1);
        }
        // AGPR groups 9..24
        AGRP(9,   0,1,2,3,     4,5,6,7)
        AGRP(10,  8,9,10,11,   12,13,14,15)
        AGRP(11,  16,17,18,19, 20,21,22,23)
        AGRP(12,  24,25,26,27, 28,29,30,31)
        AGRP(13,  32,33,34,35, 36,37,38,39)
        AGRP(14,  40,41,42,43, 44,45,46,47)
        AGRP(15,  48,49,50,51, 52,53,54,55)
        AGRP(16,  56,57,58,59, 60,61,62,63)
        AGRP(17,  64,65,66,67, 68,69,70,71)
        AGRP(18,  72,73,74,75, 76,77,78,79)
        AGRP(19,  80,81,82,83, 84,85,86,87)
        AGRP(20,  88,89,90,91, 92,93,94,95)
        AGRP(21,  96,97,98,99, 100,101,102,103)
        AGRP(22,  104,105,106,107, 108,109,110,111)
        AGRP(23,  112,113,114,115, 116,117,118,119)
        AGRP(24,  120,121,122,123, 124,125,126,127)
        // streamed groups 25..31
#define USES(kg) { uint4 hv = h4[kg]; \
        acc0 = dot2f(hv.x, sa##kg.x, acc0); acc0 = dot2f(hv.y, sa##kg.y, acc0); \
        acc0 = dot2f(hv.z, sa##kg.z, acc0); acc0 = dot2f(hv.w, sa##kg.w, acc0); \
        acc1 = dot2f(hv.x, sb##kg.x, acc1); acc1 = dot2f(hv.y, sb##kg.y, acc1); \
        acc1 = dot2f(hv.z, sb##kg.z, acc1); acc1 = dot2f(hv.w, sb##kg.w, acc1); }
        SG7(USES)
#undef USES

        if (half) { gx[j * 2] = acc0; gx[j * 2 + 1] = acc1; }
        __syncthreads();
        if (!half) {
            float gi_ = acc0, gf = acc1;
            float gg = gx[j * 2], go = gx[j * 2 + 1];
            c = fsigm(gf) * c + fsigm(gi_) * ftanh_(gg);
            float h = fsigm(go) * ftanh_(c);
            size_t orow = (size_t)(tt * BATCH + b) * 512 + dir * 256 + j;
            if (out32) out32[orow] = h;
            if (out16) out16[orow] = (_Float16)h;
            float hn = __shfl_xor(h, 1);
            if ((j & 1) == 0) h16[j >> 1] = pack2h(h, hn);
        }
        __syncthreads();
    }
}

// ---------------------------------------------------------------------------
// LayerNorm over last dim 512, fp32 in -> fp16 out. 256 thr = 4 rows.
// ---------------------------------------------------------------------------
__global__ __launch_bounds__(256) void ln_kernel(
    const float* __restrict__ in, const float* __restrict__ g,
    const float* __restrict__ b, _Float16* __restrict__ out, int rows)
{
    int row = blockIdx.x * 4 + (threadIdx.x >> 6);
    if (row >= rows) return;
    int lane = threadIdx.x & 63;
    const float4* x = (const float4*)(in + (size_t)row * 512);
    float4 v0 = x[lane * 2], v1 = x[lane * 2 + 1];
    float s = v0.x + v0.y + v0.z + v0.w + v1.x + v1.y + v1.z + v1.w;
    float sq = v0.x * v0.x + v0.y * v0.y + v0.z * v0.z + v0.w * v0.w
             + v1.x * v1.x + v1.y * v1.y + v1.z * v1.z + v1.w * v1.w;
#pragma unroll
    for (int m = 1; m < 64; m <<= 1) {
        s += __shfl_xor(s, m);
        sq += __shfl_xor(sq, m);
    }
    float mu = s * (1.0f / 512.0f);
    float var = sq * (1.0f / 512.0f) - mu * mu;
    float rs = rsqrtf(var + 1e-5f);
    const float4* g4 = (const float4*)g;
    const float4* b4 = (const float4*)b;
    f16x8 r;
    float vv[8] = {v0.x, v0.y, v0.z, v0.w, v1.x, v1.y, v1.z, v1.w};
    float4 gg0 = g4[lane * 2], gg1 = g4[lane * 2 + 1];
    float4 bb0 = b4[lane * 2], bb1 = b4[lane * 2 + 1];
    float gA[8] = {gg0.x, gg0.y, gg0.z, gg0.w, gg1.x, gg1.y, gg1.z, gg1.w};
    float bA[8] = {bb0.x, bb0.y, bb0.z, bb0.w, bb1.x, bb1.y, bb1.z, bb1.w};
#pragma unroll
    for (int q = 0; q < 8; ++q) r[q] = (_Float16)((vv[q] - mu) * rs * gA[q] + bA[q]);
    *(f16x8*)&out[(size_t)row * 512 + lane * 8] = r;
}

// ---------------------------------------------------------------------------
// CTC head: log_softmax(relu(cx) @ ctcWt) * mask. One block (128 thr) per row.
// ---------------------------------------------------------------------------
__global__ __launch_bounds__(128) void ctc_head_kernel(
    const float* __restrict__ cx, const float* __restrict__ ctcWt,
    const int* __restrict__ lens, float* __restrict__ out)
{
    int r = blockIdx.x;
    int t = r / BATCH, b = r - t * BATCH;
    int tid = threadIdx.x;
    __shared__ float xr[512];
    __shared__ float red[128];
    for (int i = tid; i < 512; i += 128) xr[i] = fmaxf(cx[(size_t)r * 512 + i], 0.0f);
    __syncthreads();
    float logit = 0.0f;
    if (tid < 80) {
#pragma unroll 8
        for (int k = 0; k < 512; ++k) logit += xr[k] * ctcWt[k * 80 + tid];
    }
    red[tid] = (tid < 80) ? logit : -1e30f;
    __syncthreads();
    for (int off = 64; off > 0; off >>= 1) {
        if (tid < off) red[tid] = fmaxf(red[tid], red[tid + off]);
        __syncthreads();
    }
    float m = red[0];
    __syncthreads();
    red[tid] = (tid < 80) ? __expf(logit - m) : 0.0f;
    __syncthreads();
    for (int off = 64; off > 0; off >>= 1) {
        if (tid < off) red[tid] += red[tid + off];
        __syncthreads();
    }
    float lsum = __logf(red[0]);
    if (tid < 80) {
        float lp = logit - m - lsum;
        out[(size_t)r * 80 + tid] = (t < lens[b]) ? lp : 0.0f;
    }
}

// ---------------------------------------------------------------------------
// Mel head: (mx @ melWt) * 6 - 6. One block (128 thr) per row.
// ---------------------------------------------------------------------------
__global__ __launch_bounds__(128) void mel_head_kernel(
    const float* __restrict__ mx, const float* __restrict__ melWt,
    float* __restrict__ out)
{
    int r = blockIdx.x;
    int tid = threadIdx.x;
    __shared__ float xr[512];
    for (int i = tid; i < 512; i += 128) xr[i] = mx[(size_t)r * 512 + i];
    __syncthreads();
    if (tid < 80) {
        float acc = 0.0f;
#pragma unroll 8
        for (int k = 0; k < 512; ++k) acc += xr[k] * melWt[k * 80 + tid];
        out[(size_t)r * 80 + tid] = acc * 6.0f - 6.0f;
    }
}

// ===========================================================================
extern "C" void kernel_launch(void* const* d_in, const int* in_sizes, int n_in,
                              void* d_out, int out_size, void* d_ws, size_t ws_size,
                              hipStream_t stream) {
    const float* mels = (const float*)d_in[0];
    const float* c1w = (const float*)d_in[1];
    const float* c1b = (const float*)d_in[2];
    const float* bn1g = (const float*)d_in[3];
    const float* bn1b = (const float*)d_in[4];
    const float* bn1m = (const float*)d_in[5];
    const float* bn1v = (const float*)d_in[6];
    const float* c2w = (const float*)d_in[7];
    const float* c2b = (const float*)d_in[8];
    const float* bn2g = (const float*)d_in[9];
    const float* bn2b = (const float*)d_in[10];
    const float* bn2m = (const float*)d_in[11];
    const float* bn2v = (const float*)d_in[12];
    const float* eWih = (const float*)d_in[13];
    const float* eWhh = (const float*)d_in[14];
    const float* eb   = (const float*)d_in[15];
    const float* elng = (const float*)d_in[16];
    const float* elnb = (const float*)d_in[17];
    const float* cWih = (const float*)d_in[18];
    const float* cWhh = (const float*)d_in[19];
    const float* cb   = (const float*)d_in[20];
    const float* ctcW = (const float*)d_in[21];
    const float* btlW = (const float*)d_in[22];
    const float* lng  = (const float*)d_in[23];
    const float* lnb  = (const float*)d_in[24];
    const float* dWih = (const float*)d_in[25];
    const float* dWhh = (const float*)d_in[26];
    const float* db   = (const float*)d_in[27];
    const float* melW = (const float*)d_in[28];
    const int* mel_lengths = (const int*)d_in[29];

    float* out = (float*)d_out;          // [SROWS*80 mel][SROWS*80 logprob]
    float* ws = (float*)d_ws;

    // ---- workspace layout ----
    float* preB = ws;                                   // 32,768,000 f32
    float* s32  = ws + 32768000;                        //  8,192,000 f32
    _Float16* f0 = (_Float16*)(ws + 40960000);          //  8,192,000 f16 each
    _Float16* f1 = f0 + 8192000;
    _Float16* f2 = f1 + 8192000;
    _Float16* f3 = f2 + 8192000;
    _Float16* BP    = f3 + 8192000;                     // 6 x 1,048,576 f16
    _Float16* BPbtl = BP + 6ull * 1048576;              // 524,288 f16
    _Float16* BPcv  = BPbtl + 524288;                   // 5 x 262,144 f16
    u32* wpAll = (u32*)(BPcv + 5ull * 262144);          // 6 x 262,144 u32
    float* ctcT = (float*)(wpAll + 6ull * 262144);      // 40,960 f32
    float* melT = ctcT + 40960;                         // 40,960 f32

    (void)hipFuncSetAttribute((const void*)lstm_scan,
                              hipFuncAttributeMaxDynamicSharedMemorySize, SCAN_LDS);

    // ---- weight prep ----
    transpose_kernel<<<160, 256, 0, stream>>>(ctcW, ctcT, 80, 512);
    transpose_kernel<<<160, 256, 0, stream>>>(melW, melT, 80, 512);
    prep_whh_kernel<<<2048, 256, 0, stream>>>(eWhh, wpAll + 0ull * 262144, 2 * 262144);
    prep_whh_kernel<<<2048, 256, 0, stream>>>(cWhh, wpAll + 2ull * 262144, 2 * 262144);
    prep_whh_kernel<<<2048, 256, 0, stream>>>(dWhh, wpAll + 4ull * 262144, 2 * 262144);
    for (int l = 0; l < 2; ++l) {
        pack_b_kernel<<<1024, 256, 0, stream>>>(eWih + (size_t)l * 1048576,
                                                BP + (size_t)(0 + l) * 1048576, 2048, 512, 512, 1, 0);
        pack_b_kernel<<<1024, 256, 0, stream>>>(cWih + (size_t)l * 1048576,
                                                BP + (size_t)(2 + l) * 1048576, 2048, 512, 512, 1, 0);
        pack_b_kernel<<<1024, 256, 0, stream>>>(dWih + (size_t)l * 1048576,
                                                BP + (size_t)(4 + l) * 1048576, 2048, 512, 512, 1, 0);
    }
    pack_b_kernel<<<1024, 256, 0, stream>>>(btlW, BPbtl, 512, 1024, 1024, 1, 0);
    for (int kph = 0; kph < 5; ++kph)
        pack_b_kernel<<<512, 256, 0, stream>>>(c2w, BPcv + (size_t)kph * 262144,
                                               512, 512, 2560, 5, kph);

    // ---- prenet ----
    conv1_kernel<<<dim3(16, 16), 256, 0, stream>>>(mels, c1w, c1b, bn1g, bn1b, bn1m, bn1v, s32);
    relayout_kernel<<<dim3(16, 8, 16), 256, 0, stream>>>(s32, f0);
    gemm_mfma<1><<<dim3(125, 4), 512, 0, stream>>>(f0, nullptr, 0, (const uint4*)BPcv, nullptr,
                                                   nullptr, f1, c2b, bn2g, bn2b, bn2m, bn2v, 512, 2560);

    dim3 gN2048(125, 16), gN512(125, 4);
    const uint4* BPu = (const uint4*)BP;
    // ---- encoder ----
    gemm_mfma<0><<<gN2048, 512, 0, stream>>>(f1, nullptr, 512, BPu + 0ull * 131072, eb,
                                             preB, nullptr, nullptr, nullptr, nullptr, nullptr, nullptr, 2048, 512);
    lstm_scan<<<32, 512, SCAN_LDS, stream>>>(preB, (const uint4*)(wpAll + 0ull * 262144), nullptr, f2);
    gemm_mfma<0><<<gN2048, 512, 0, stream>>>(f2, nullptr, 512, BPu + 1ull * 131072, eb + 2048,
                                             preB, nullptr, nullptr, nullptr, nullptr, nullptr, nullptr, 2048, 512);
    lstm_scan<<<32, 512, SCAN_LDS, stream>>>(preB, (const uint4*)(wpAll + 1ull * 262144), s32, nullptr);
    ln_kernel<<<4000, 256, 0, stream>>>(s32, elng, elnb, f2, SROWS);   // f2 = h (fp16)
    // ---- ctc decoder ----
    gemm_mfma<0><<<gN2048, 512, 0, stream>>>(f2, nullptr, 512, BPu + 2ull * 131072, cb,
                                             preB, nullptr, nullptr, nullptr, nullptr, nullptr, nullptr, 2048, 512);
    lstm_scan<<<32, 512, SCAN_LDS, stream>>>(preB, (const uint4*)(wpAll + 2ull * 262144), nullptr, f3);
    gemm_mfma<0><<<gN2048, 512, 0, stream>>>(f3, nullptr, 512, BPu + 3ull * 131072, cb + 2048,
                                             preB, nullptr, nullptr, nullptr, nullptr, nullptr, nullptr, 2048, 512);
    lstm_scan<<<32, 512, SCAN_LDS, stream>>>(preB, (const uint4*)(wpAll + 3ull * 262144), s32, f1); // cx
    ctc_head_kernel<<<SROWS, 128, 0, stream>>>(s32, ctcT, mel_lengths, out + (size_t)SROWS * 80);
    // ---- bottleneck: [h | cx] @ btlW.T -> LN ----
    gemm_mfma<0><<<gN512, 512, 0, stream>>>(f2, f1, 512, (const uint4*)BPbtl, nullptr,
                                            preB, nullptr, nullptr, nullptr, nullptr, nullptr, nullptr, 512, 1024);
    ln_kernel<<<4000, 256, 0, stream>>>(preB, lng, lnb, f3, SROWS);    // f3 = bottleneck (fp16)
    // ---- mel decoder ----
    gemm_mfma<0><<<gN2048, 512, 0, stream>>>(f3, nullptr, 512, BPu + 4ull * 131072, db,
                                             preB, nullptr, nullptr, nullptr, nullptr, nullptr, nullptr, 2048, 512);
    lstm_scan<<<32, 512, SCAN_LDS, stream>>>(preB, (const uint4*)(wpAll + 4ull * 262144), nullptr, f2);
    gemm_mfma<0><<<gN2048, 512, 0, stream>>>(f2, nullptr, 512, BPu + 5ull * 131072, db + 2048,
                                             preB, nullptr, nullptr, nullptr, nullptr, nullptr, nullptr, 2048, 512);
    lstm_scan<<<32, 512, SCAN_LDS, stream>>>(preB, (const uint4*)(wpAll + 5ull * 262144), s32, nullptr); // mx
    mel_head_kernel<<<SROWS, 128, 0, stream>>>(s32, melT, out);
}